// Round 1
// 745.312 us; speedup vs baseline: 1.0516x; 1.0516x over previous
//
#include <hip/hip_runtime.h>
#include <hip/hip_bf16.h>
#include <cstdint>
#include <cstddef>
#include <cmath>

// Problem constants (fixed by the reference)
#define N0C 600000
#define N1C 100000
#define N2C 10000
#define N3C 1000
#define E0C 1000000
#define E1C 100000
#define E2C 10000

typedef unsigned short u16;
typedef unsigned int u32;
typedef __attribute__((ext_vector_type(8))) short bf16x8;
typedef __attribute__((ext_vector_type(4))) float f32x4;

__device__ __forceinline__ u16 f2b(float x) {
  u32 u = __builtin_bit_cast(u32, x);
  u32 r = (u + 0x7fffu + ((u >> 16) & 1u)) >> 16;  // RNE
  return (u16)r;
}
// hardware RNE convert (compiler packs pairs into v_cvt_pk_bf16_f32)
__device__ __forceinline__ u16 f2b_hw(float x) {
  __hip_bfloat16 h = __float2bfloat16(x);
  u16 r;
  __builtin_memcpy(&r, &h, 2);
  return r;
}
__device__ __forceinline__ float b2f(u16 h) {
  u32 u = ((u32)h) << 16;
  return __builtin_bit_cast(float, u);
}

// -------------------- fused CSR build (all 3 layers) --------------------
__global__ __launch_bounds__(256) void hist3(
    const int* __restrict__ d0, const int* __restrict__ d1,
    const int* __restrict__ d2, int* __restrict__ c0, int* __restrict__ c1,
    int* __restrict__ c2) {
  int i = blockIdx.x * blockDim.x + threadIdx.x;
  if (i < E0C) atomicAdd(&c0[d0[i]], 1);
  else if (i < E0C + E1C) atomicAdd(&c1[d1[i - E0C]], 1);
  else if (i < E0C + E1C + E2C) atomicAdd(&c2[d2[i - E0C - E1C]], 1);
}

// blocks [0,98) -> seg0, [98,108) -> seg1, [108,109) -> seg2
__global__ __launch_bounds__(256) void scan_block3(
    int* __restrict__ c0, int* __restrict__ c1, int* __restrict__ c2,
    int* __restrict__ p0, int* __restrict__ p1, int* __restrict__ p2) {
  __shared__ int sdata[256];
  const int b = blockIdx.x;
  int* data; int n; int* partials; int lb;
  if (b < 98)       { data = c0; n = N1C; partials = p0; lb = b; }
  else if (b < 108) { data = c1; n = N2C; partials = p1; lb = b - 98; }
  else              { data = c2; n = N3C; partials = p2; lb = b - 108; }
  const int t = threadIdx.x;
  const int idx = lb * 1024 + t * 4;
  int v[4];
  int sum = 0;
#pragma unroll
  for (int k = 0; k < 4; k++) {
    int x = (idx + k < n) ? data[idx + k] : 0;
    v[k] = x; sum += x;
  }
  sdata[t] = sum;
  __syncthreads();
  for (int off = 1; off < 256; off <<= 1) {
    int x = (t >= off) ? sdata[t - off] : 0;
    __syncthreads();
    sdata[t] += x;
    __syncthreads();
  }
  int run = (t > 0) ? sdata[t - 1] : 0;
#pragma unroll
  for (int k = 0; k < 4; k++) {
    run += v[k];
    if (idx + k < n) data[idx + k] = run;  // inclusive, in place
  }
  if (t == 255) partials[lb] = sdata[255];
}

// block s scans partials of segment s (sizes 98,10,1), 128 threads
__global__ __launch_bounds__(128) void scan_partials3(
    int* __restrict__ p0, int* __restrict__ p1, int* __restrict__ p2) {
  __shared__ int sdata[128];
  int* p; int nb;
  if (blockIdx.x == 0)      { p = p0; nb = 98; }
  else if (blockIdx.x == 1) { p = p1; nb = 10; }
  else                      { p = p2; nb = 1; }
  const int t = threadIdx.x;
  sdata[t] = (t < nb) ? p[t] : 0;
  __syncthreads();
  for (int off = 1; off < 128; off <<= 1) {
    int x = (t >= off) ? sdata[t - off] : 0;
    __syncthreads();
    sdata[t] += x;
    __syncthreads();
  }
  int ex = (t > 0) ? sdata[t - 1] : 0;
  if (t < nb) p[t] = ex;
}

__global__ __launch_bounds__(256) void addoff3(
    const int* __restrict__ c0, const int* __restrict__ c1,
    const int* __restrict__ c2, const int* __restrict__ p0,
    const int* __restrict__ p1, const int* __restrict__ p2,
    int* __restrict__ o0, int* __restrict__ o1, int* __restrict__ o2) {
  int i = blockIdx.x * blockDim.x + threadIdx.x;
  if (i < N1C) {
    o0[i + 1] = c0[i] + p0[i >> 10];
    if (i == 0) o0[0] = 0;
  } else if (i < N1C + N2C) {
    int j = i - N1C;
    o1[j + 1] = c1[j] + p1[j >> 10];
    if (j == 0) o1[0] = 0;
  } else if (i < N1C + N2C + N3C) {
    int j = i - N1C - N2C;
    o2[j + 1] = c2[j] + p2[j >> 10];
    if (j == 0) o2[0] = 0;
  }
}

__global__ __launch_bounds__(256) void fill3(
    const int* __restrict__ s0, const int* __restrict__ d0,
    const int* __restrict__ s1, const int* __restrict__ d1,
    const int* __restrict__ s2, const int* __restrict__ d2,
    const int* __restrict__ o0, const int* __restrict__ o1,
    const int* __restrict__ o2, int* __restrict__ u0, int* __restrict__ u1,
    int* __restrict__ u2, int* __restrict__ e0, int* __restrict__ e1,
    int* __restrict__ e2) {
  int i = blockIdx.x * blockDim.x + threadIdx.x;
  if (i < E0C) {
    int d = d0[i]; int p = atomicAdd(&u0[d], 1); e0[o0[d] + p] = s0[i];
  } else if (i < E0C + E1C) {
    int j = i - E0C;
    int d = d1[j]; int p = atomicAdd(&u1[d], 1); e1[o1[d] + p] = s1[j];
  } else if (i < E0C + E1C + E2C) {
    int j = i - E0C - E1C;
    int d = d2[j]; int p = atomicAdd(&u2[d], 1); e2[o2[d] + p] = s2[j];
  }
}

// -------------------- conversions --------------------
// both weight transposes in one kernel:
// Wt0[n][k] n<256,k<256 from (Wl0,Wr0,Kh=128); Wt1[n][k] n<256,k<512
__global__ __launch_bounds__(256) void cvt_wt2(
    const float* __restrict__ Wl0, const float* __restrict__ Wr0,
    const float* __restrict__ Wl1, const float* __restrict__ Wr1,
    u16* __restrict__ Wt0, u16* __restrict__ Wt1) {
  int idx = blockIdx.x * blockDim.x + threadIdx.x;
  if (idx < 256 * 256) {
    int n = idx >> 8, k = idx & 255;
    float v = (k < 128) ? Wl0[(size_t)k * 256 + n] : Wr0[(size_t)(k - 128) * 256 + n];
    Wt0[idx] = f2b(v);
  } else if (idx < 256 * 256 + 256 * 512) {
    int j = idx - 256 * 256;
    int n = j >> 9, k = j & 511;
    float v = (k < 256) ? Wl1[(size_t)k * 256 + n] : Wr1[(size_t)(k - 256) * 256 + n];
    Wt1[j] = f2b(v);
  }
}

// -------------------- CSR gather-mean --------------------
// dim=128 f32 source: row = 512B = 64 lanes x float2. 4x unroll.
// Accumulate in f32 from full-precision x, emit bf16 mean.
__global__ __launch_bounds__(256) void gather128_f32(
    const float* __restrict__ X, const int* __restrict__ off,
    const int* __restrict__ esrc, int Nt, u16* __restrict__ mean) {
  int w = (blockIdx.x * blockDim.x + threadIdx.x) >> 6;
  int lane = threadIdx.x & 63;
  if (w >= Nt) return;
  int s = off[w], e = off[w + 1];
  float a0 = 0.f, a1 = 0.f;
  int j = s;
  for (; j + 3 < e; j += 4) {
    float2 r0 = *(const float2*)(X + (size_t)esrc[j + 0] * 128 + lane * 2);
    float2 r1 = *(const float2*)(X + (size_t)esrc[j + 1] * 128 + lane * 2);
    float2 r2 = *(const float2*)(X + (size_t)esrc[j + 2] * 128 + lane * 2);
    float2 r3 = *(const float2*)(X + (size_t)esrc[j + 3] * 128 + lane * 2);
    a0 += r0.x + r1.x + r2.x + r3.x;
    a1 += r0.y + r1.y + r2.y + r3.y;
  }
  for (; j < e; j++) {
    float2 r = *(const float2*)(X + (size_t)esrc[j] * 128 + lane * 2);
    a0 += r.x;
    a1 += r.y;
  }
  float inv = 1.0f / fmaxf((float)(e - s), 1.0f);
  u32 p = ((u32)f2b(a1 * inv) << 16) | (u32)f2b(a0 * inv);
  ((u32*)(mean + (size_t)w * 128))[lane] = p;
}

// dim=256 bf16: row = 512B = 64 lanes x ushort4. 4x unroll.
__global__ __launch_bounds__(256) void gather256_bf16(
    const u16* __restrict__ X, const int* __restrict__ off,
    const int* __restrict__ esrc, int Nt, u16* __restrict__ mean) {
  int w = (blockIdx.x * blockDim.x + threadIdx.x) >> 6;
  int lane = threadIdx.x & 63;
  if (w >= Nt) return;
  int s = off[w], e = off[w + 1];
  float a0 = 0.f, a1 = 0.f, a2 = 0.f, a3 = 0.f;
  int j = s;
  for (; j + 3 < e; j += 4) {
    ushort4 v0 = *(const ushort4*)(X + (size_t)esrc[j + 0] * 256 + lane * 4);
    ushort4 v1 = *(const ushort4*)(X + (size_t)esrc[j + 1] * 256 + lane * 4);
    ushort4 v2 = *(const ushort4*)(X + (size_t)esrc[j + 2] * 256 + lane * 4);
    ushort4 v3 = *(const ushort4*)(X + (size_t)esrc[j + 3] * 256 + lane * 4);
    a0 += b2f(v0.x) + b2f(v1.x) + b2f(v2.x) + b2f(v3.x);
    a1 += b2f(v0.y) + b2f(v1.y) + b2f(v2.y) + b2f(v3.y);
    a2 += b2f(v0.z) + b2f(v1.z) + b2f(v2.z) + b2f(v3.z);
    a3 += b2f(v0.w) + b2f(v1.w) + b2f(v2.w) + b2f(v3.w);
  }
  for (; j < e; j++) {
    ushort4 v0 = *(const ushort4*)(X + (size_t)esrc[j] * 256 + lane * 4);
    a0 += b2f(v0.x); a1 += b2f(v0.y); a2 += b2f(v0.z); a3 += b2f(v0.w);
  }
  float inv = 1.0f / fmaxf((float)(e - s), 1.0f);
  ushort4 o;
  o.x = f2b(a0 * inv); o.y = f2b(a1 * inv); o.z = f2b(a2 * inv); o.w = f2b(a3 * inv);
  *(ushort4*)(mean + (size_t)w * 256 + lane * 4) = o;
}

// -------------------- bf16 MFMA GEMM (LDS-free, concat-K) --------------------
// generic: both A halves bf16 (used for layer 1)
__global__ __launch_bounds__(256) void gemm_mfma(
    const u16* __restrict__ A1, const u16* __restrict__ A2, int Kh,
    const u16* __restrict__ Wt, const float* __restrict__ bias,
    u16* __restrict__ C, int M, int do_relu) {
  const int tid = threadIdx.x;
  const int wave = tid >> 6, lane = tid & 63;
  const int lr = lane & 15, quad = lane >> 4;
  const int wr = wave >> 1, wc = wave & 1;
  const int rowBase = blockIdx.x * 128 + wr * 64;
  const int colBase = blockIdx.y * 128 + wc * 64;
  const int Ktot = 2 * Kh;

  f32x4 acc[4][4] = {};

  size_t aoff[4];
#pragma unroll
  for (int mt = 0; mt < 4; mt++) {
    int r = rowBase + mt * 16 + lr;
    if (r >= M) r = M - 1;
    aoff[mt] = (size_t)r * Kh;
  }
  const u16* wrow[4];
  float bs[4];
#pragma unroll
  for (int nt = 0; nt < 4; nt++) {
    int n = colBase + nt * 16 + lr;
    wrow[nt] = Wt + (size_t)n * Ktot;
    bs[nt] = bias[n];
  }

#pragma unroll
  for (int half = 0; half < 2; half++) {
    const u16* Asrc = half ? A2 : A1;
    const int kb = half * Kh;
    for (int kt = 0; kt < Kh; kt += 32) {
      bf16x8 af[4], bfr[4];
#pragma unroll
      for (int mt = 0; mt < 4; mt++)
        af[mt] = *(const bf16x8*)(Asrc + aoff[mt] + kt + quad * 8);
#pragma unroll
      for (int nt = 0; nt < 4; nt++)
        bfr[nt] = *(const bf16x8*)(wrow[nt] + kb + kt + quad * 8);
#pragma unroll
      for (int mt = 0; mt < 4; mt++)
#pragma unroll
        for (int nt = 0; nt < 4; nt++)
          acc[mt][nt] = __builtin_amdgcn_mfma_f32_16x16x32_bf16(
              af[mt], bfr[nt], acc[mt][nt], 0, 0, 0);
    }
  }

  // C/D layout: col=lane&15, row=quad*4+reg
#pragma unroll
  for (int mt = 0; mt < 4; mt++) {
#pragma unroll
    for (int reg = 0; reg < 4; reg++) {
      int row = rowBase + mt * 16 + quad * 4 + reg;
      if (row < M) {
#pragma unroll
        for (int nt = 0; nt < 4; nt++) {
          float v = acc[mt][nt][reg] + bs[nt];
          if (do_relu) v = fmaxf(v, 0.f);
          C[(size_t)row * 256 + colBase + nt * 16 + lr] = f2b(v);
        }
      }
    }
  }
}

// layer-0 variant: A1 = mean0 (bf16, K=128), A2 = x (f32, converted in-register)
__global__ __launch_bounds__(256) void gemm_mfma_l0(
    const u16* __restrict__ A1, const float* __restrict__ A2,
    const u16* __restrict__ Wt, const float* __restrict__ bias,
    u16* __restrict__ C, int M) {
  const int tid = threadIdx.x;
  const int wave = tid >> 6, lane = tid & 63;
  const int lr = lane & 15, quad = lane >> 4;
  const int wr = wave >> 1, wc = wave & 1;
  const int rowBase = blockIdx.x * 128 + wr * 64;
  const int colBase = blockIdx.y * 128 + wc * 64;

  f32x4 acc[4][4] = {};

  int rrow[4];
#pragma unroll
  for (int mt = 0; mt < 4; mt++) {
    int r = rowBase + mt * 16 + lr;
    if (r >= M) r = M - 1;
    rrow[mt] = r;
  }
  const u16* wrow[4];
  float bs[4];
#pragma unroll
  for (int nt = 0; nt < 4; nt++) {
    int n = colBase + nt * 16 + lr;
    wrow[nt] = Wt + (size_t)n * 256;
    bs[nt] = bias[n];
  }

  // half 0: mean (bf16), Wt k in [0,128)
  for (int kt = 0; kt < 128; kt += 32) {
    bf16x8 af[4], bfr[4];
#pragma unroll
    for (int mt = 0; mt < 4; mt++)
      af[mt] = *(const bf16x8*)(A1 + (size_t)rrow[mt] * 128 + kt + quad * 8);
#pragma unroll
    for (int nt = 0; nt < 4; nt++)
      bfr[nt] = *(const bf16x8*)(wrow[nt] + kt + quad * 8);
#pragma unroll
    for (int mt = 0; mt < 4; mt++)
#pragma unroll
      for (int nt = 0; nt < 4; nt++)
        acc[mt][nt] = __builtin_amdgcn_mfma_f32_16x16x32_bf16(
            af[mt], bfr[nt], acc[mt][nt], 0, 0, 0);
  }
  // half 1: x rows (f32 -> bf16 in-register), Wt k in [128,256)
  for (int kt = 0; kt < 128; kt += 32) {
    bf16x8 af[4], bfr[4];
#pragma unroll
    for (int mt = 0; mt < 4; mt++) {
      const float* s = A2 + (size_t)rrow[mt] * 128 + kt + quad * 8;
      float4 v0 = *(const float4*)s;
      float4 v1 = *(const float4*)(s + 4);
      bf16x8 t;
      t[0] = (short)f2b_hw(v0.x); t[1] = (short)f2b_hw(v0.y);
      t[2] = (short)f2b_hw(v0.z); t[3] = (short)f2b_hw(v0.w);
      t[4] = (short)f2b_hw(v1.x); t[5] = (short)f2b_hw(v1.y);
      t[6] = (short)f2b_hw(v1.z); t[7] = (short)f2b_hw(v1.w);
      af[mt] = t;
    }
#pragma unroll
    for (int nt = 0; nt < 4; nt++)
      bfr[nt] = *(const bf16x8*)(wrow[nt] + 128 + kt + quad * 8);
#pragma unroll
    for (int mt = 0; mt < 4; mt++)
#pragma unroll
      for (int nt = 0; nt < 4; nt++)
        acc[mt][nt] = __builtin_amdgcn_mfma_f32_16x16x32_bf16(
            af[mt], bfr[nt], acc[mt][nt], 0, 0, 0);
  }

  // C/D layout: col=lane&15, row=quad*4+reg; relu fused
#pragma unroll
  for (int mt = 0; mt < 4; mt++) {
#pragma unroll
    for (int reg = 0; reg < 4; reg++) {
      int row = rowBase + mt * 16 + quad * 4 + reg;
      if (row < M) {
#pragma unroll
        for (int nt = 0; nt < 4; nt++) {
          float v = fmaxf(acc[mt][nt][reg] + bs[nt], 0.f);
          C[(size_t)row * 256 + colBase + nt * 16 + lr] = f2b(v);
        }
      }
    }
  }
}

// -------------------- layer 2 + log_softmax (bf16 inputs) --------------------
__global__ __launch_bounds__(64) void layer2_lsm(
    const u16* __restrict__ mean2, const u16* __restrict__ h2,
    const float* __restrict__ Wl2, const float* __restrict__ Wr2,
    const float* __restrict__ b2, float* __restrict__ out) {
  __shared__ float arow[512];
  const int i = blockIdx.x;
  const int lane = threadIdx.x;
  for (int t = lane; t < 256; t += 64) {
    arow[t] = b2f(mean2[(size_t)i * 256 + t]);
    arow[256 + t] = b2f(h2[(size_t)i * 256 + t]);
  }
  __syncthreads();
  float acc = 0.0f;
  if (lane < 47) {
    acc = b2[lane];
#pragma unroll 4
    for (int k = 0; k < 256; k++) acc += arow[k] * Wl2[k * 47 + lane];
#pragma unroll 4
    for (int k = 0; k < 256; k++) acc += arow[256 + k] * Wr2[k * 47 + lane];
  }
  float v = (lane < 47) ? acc : -INFINITY;
#pragma unroll
  for (int off = 32; off >= 1; off >>= 1) v = fmaxf(v, __shfl_xor(v, off, 64));
  float e = (lane < 47) ? expf(acc - v) : 0.0f;
  float s = e;
#pragma unroll
  for (int off = 32; off >= 1; off >>= 1) s += __shfl_xor(s, off, 64);
  if (lane < 47) out[(size_t)i * 47 + lane] = acc - v - logf(s);
}

// -------------------- launch --------------------
extern "C" void kernel_launch(void* const* d_in, const int* in_sizes, int n_in,
                              void* d_out, int out_size, void* d_ws, size_t ws_size,
                              hipStream_t stream) {
  (void)in_sizes; (void)n_in; (void)out_size; (void)ws_size;
  const float* x   = (const float*)d_in[0];
  const int* src0  = (const int*)d_in[1];
  const int* dst0  = (const int*)d_in[2];
  const int* src1  = (const int*)d_in[3];
  const int* dst1  = (const int*)d_in[4];
  const int* src2  = (const int*)d_in[5];
  const int* dst2  = (const int*)d_in[6];
  const float* Wl0 = (const float*)d_in[7];
  const float* Wr0 = (const float*)d_in[8];
  const float* b0  = (const float*)d_in[9];
  const float* Wl1 = (const float*)d_in[10];
  const float* Wr1 = (const float*)d_in[11];
  const float* b1  = (const float*)d_in[12];
  const float* Wl2 = (const float*)d_in[13];
  const float* Wr2 = (const float*)d_in[14];
  const float* b2  = (const float*)d_in[15];

  // ---- workspace layout (~92 MB; 256B-aligned blocks); no full-x bf16 copy ----
  char* p = (char*)d_ws;
  u16* mean0 = (u16*)p; p += (size_t)N1C * 128 * 2;   // 25.6 MB
  u16* h1    = (u16*)p; p += (size_t)N1C * 256 * 2;   // 51.2 MB
  u16* mean1 = (u16*)p; p += (size_t)N2C * 256 * 2;   // 5.12 MB
  u16* h2    = (u16*)p; p += (size_t)N2C * 256 * 2;   // 5.12 MB
  u16* mean2 = (u16*)p; p += (size_t)N3C * 256 * 2;   // 0.512 MB
  u16* Wt0   = (u16*)p; p += (size_t)256 * 256 * 2;   // 128 KB
  u16* Wt1   = (u16*)p; p += (size_t)256 * 512 * 2;   // 256 KB
  // contiguous cnt/cur block -> single memset (222,000 ints)
  int* cnt0  = (int*)p;
  int* cur0  = cnt0 + 100000;
  int* cnt1  = cur0 + 100000;
  int* cur1  = cnt1 + 10000;
  int* cnt2  = cur1 + 10000;
  int* cur2  = cnt2 + 1000;
  int* off0  = cur2 + 1000 + 48;   // pad to 256B boundary
  int* off1  = off0 + 100096;
  int* off2  = off1 + 10112;
  int* part0 = off2 + 1088;
  int* part1 = part0 + 128;
  int* part2 = part1 + 128;
  int* esrc0 = part2 + 128;
  int* esrc1 = esrc0 + 1000000;
  int* esrc2 = esrc1 + 100000;
  float* out = (float*)d_out;

  // ---- fused CSR build (all layers) ----
  hipMemsetAsync(cnt0, 0, (size_t)222000 * 4, stream);
  hist3<<<(E0C + E1C + E2C + 255) / 256, 256, 0, stream>>>(
      dst0, dst1, dst2, cnt0, cnt1, cnt2);
  scan_block3<<<109, 256, 0, stream>>>(cnt0, cnt1, cnt2, part0, part1, part2);
  scan_partials3<<<3, 128, 0, stream>>>(part0, part1, part2);
  addoff3<<<(N1C + N2C + N3C + 255) / 256, 256, 0, stream>>>(
      cnt0, cnt1, cnt2, part0, part1, part2, off0, off1, off2);
  fill3<<<(E0C + E1C + E2C + 255) / 256, 256, 0, stream>>>(
      src0, dst0, src1, dst1, src2, dst2, off0, off1, off2,
      cur0, cur1, cur2, esrc0, esrc1, esrc2);

  // ---- weight transposes ----
  cvt_wt2<<<(256 * 256 + 256 * 512 + 255) / 256, 256, 0, stream>>>(
      Wl0, Wr0, Wl1, Wr1, Wt0, Wt1);

  // ---- layer 0 (gather straight from f32 x; GEMM converts x in-register) ----
  gather128_f32<<<N1C / 4, 256, 0, stream>>>(x, off0, esrc0, N1C, mean0);
  gemm_mfma_l0<<<dim3(782, 2), 256, 0, stream>>>(mean0, x, Wt0, b0, h1, N1C);

  // ---- layer 1 ----
  gather256_bf16<<<N2C / 4, 256, 0, stream>>>(h1, off1, esrc1, N2C, mean1);
  gemm_mfma<<<dim3(79, 2), 256, 0, stream>>>(mean1, h1, 256, Wt1, b1, h2, N2C, 1);

  // ---- layer 2 + log_softmax ----
  gather256_bf16<<<N3C / 4, 256, 0, stream>>>(h2, off2, esrc2, N3C, mean2);
  layer2_lsm<<<N3C, 64, 0, stream>>>(mean2, h2, Wl2, Wr2, b2, out);
}